// Round 9
// baseline (291.975 us; speedup 1.0000x reference)
//
#include <hip/hip_runtime.h>
#include <math.h>

#define NN 16384      // B*S nodes
#define DD 256        // model dim
#define HH 8          // heads
#define EE 262144     // edges
#define D3 768        // 3*D
#define QSCALE 0.17677669529663687f   // 1/sqrt(32)
#define EXPN1 0.36787944117144233f    // exp(-1)
#define LN_EPS 1e-12f

typedef short bf16x8 __attribute__((ext_vector_type(8)));
typedef float f32x4 __attribute__((ext_vector_type(4)));
typedef float f32x2 __attribute__((ext_vector_type(2)));
typedef unsigned u32x4 __attribute__((ext_vector_type(4)));
typedef unsigned u32x2 __attribute__((ext_vector_type(2)));
typedef unsigned short u16;
typedef unsigned char u8;

// ---- bf16 helpers ----
__device__ __forceinline__ float bf_lo(unsigned u) { return __uint_as_float(u << 16); }
__device__ __forceinline__ float bf_hi(unsigned u) { return __uint_as_float(u & 0xffff0000u); }
__device__ __forceinline__ float bf16u(u16 u) { return __uint_as_float(((unsigned)u) << 16); }
__device__ __forceinline__ unsigned f2bf(float f) {  // RNE
    unsigned b = __float_as_uint(f);
    return (b + 0x7fffu + ((b >> 16) & 1u)) >> 16;
}
__device__ __forceinline__ unsigned pack2bf(float lo, float hi) {
    return f2bf(lo) | (f2bf(hi) << 16);
}
// ---- fp8 e4m3 helpers (HW cvt) ----
__device__ __forceinline__ u8 f2fp8(float v) {
    return (u8)(__builtin_amdgcn_cvt_pk_fp8_f32(v, v, 0, false) & 0xff);
}

// ---------------- prep: hconv (4096 blk) + wconvQ (768) + wconvO (256) + hist (1024) ----
__global__ void prep_kernel(const float* __restrict__ hidden, unsigned* __restrict__ hidb,
                            const float* __restrict__ Wqkv, const float* __restrict__ bqkv,
                            u16* __restrict__ WtQ, float* __restrict__ biasq,
                            const float* __restrict__ Wo, const float* __restrict__ bo,
                            u16* __restrict__ WtO, float* __restrict__ biaso,
                            const int* __restrict__ dst, int* __restrict__ deg) {
    int b = blockIdx.x;
    if (b < 4096) {
        int gid = b * 256 + threadIdx.x;
        float4 v = *(const float4*)(hidden + (size_t)gid * 4);
        *(uint2*)(hidb + (size_t)gid * 2) = make_uint2(pack2bf(v.x, v.y), pack2bf(v.z, v.w));
    } else if (b < 4864) {
        int gid = (b - 4096) * 256 + threadIdx.x;
        int n = gid >> 8, k = gid & 255;
        float s = (n < DD) ? QSCALE : 1.0f;
        WtQ[(size_t)n * 256 + k] = (u16)f2bf(Wqkv[(size_t)k * D3 + n] * s);
        if (k == 0) biasq[n] = bqkv[n] * s;
    } else if (b < 5120) {
        int gid = (b - 4864) * 256 + threadIdx.x;
        int n = gid >> 8, k = gid & 255;
        WtO[(size_t)n * 256 + k] = (u16)f2bf(Wo[(size_t)k * DD + n]);
        if (k == 0) biaso[n] = bo[n];
    } else {
        int e = (b - 5120) * 256 + threadIdx.x;
        atomicAdd(&deg[dst[e]], 1);
    }
}

// ---------------- scan (single block, 1024 threads, 16 nodes each) ----------------
__global__ __launch_bounds__(1024) void scan_kernel(const int* __restrict__ deg,
                                                    int* __restrict__ offs,
                                                    int* __restrict__ cursor, int n) {
    __shared__ int part[1024];
    int t = threadIdx.x;
    int base = t * 16;
    int local[16];
    int s = 0;
    #pragma unroll
    for (int i = 0; i < 16; ++i) { local[i] = s; s += deg[base + i]; }
    part[t] = s;
    __syncthreads();
    for (int d = 1; d < 1024; d <<= 1) {
        int add = (t >= d) ? part[t - d] : 0;
        __syncthreads();
        part[t] += add;
        __syncthreads();
    }
    int excl = part[t] - s;
    #pragma unroll
    for (int i = 0; i < 16; ++i) {
        offs[base + i] = excl + local[i];
        cursor[base + i] = excl + local[i];
    }
    if (t == 1023) offs[n] = excl + s;
}

// ---------------- fused: gemm1 (blocks 0..767) + scatter (blocks 768..1791) ----------------
__global__ __launch_bounds__(256) void gemm1_scatter_kernel(
        const u16* __restrict__ Ab, const u16* __restrict__ Bt,
        const float* __restrict__ bias,
        u16* __restrict__ qb, u8* __restrict__ kb8,
        u8* __restrict__ h8, u16* __restrict__ gb,
        const int* __restrict__ src, const int* __restrict__ dst,
        int* __restrict__ cursor, int* __restrict__ srcs) {
    __shared__ u16 As[128 * 40];
    __shared__ u16 Bs[128 * 40];
    const int tid = threadIdx.x;
    if (blockIdx.x >= 768) {                  // ---- scatter role ----
        int e = (blockIdx.x - 768) * 256 + tid;
        int pos = atomicAdd(&cursor[dst[e]], 1);
        srcs[pos] = src[e];
        return;
    }
    // ---- gemm1 role ----
    const int n0 = (blockIdx.x % 6) * 128;
    const int m0 = (blockIdx.x / 6) * 128;
    const int wave = tid >> 6, lane = tid & 63;
    const int wr = wave >> 1, wc = wave & 1;
    const int lm = lane & 15, quad = lane >> 4;

    f32x4 acc[4][4] = {};
    const int r0 = tid >> 2;
    const int c8 = (tid & 3) * 8;

    for (int k0 = 0; k0 < 256; k0 += 32) {
        #pragma unroll
        for (int s = 0; s < 2; ++s) {
            int r = r0 + s * 64;
            *(uint4*)&As[r * 40 + c8] = *(const uint4*)(Ab + (size_t)(m0 + r) * 256 + k0 + c8);
            *(uint4*)&Bs[r * 40 + c8] = *(const uint4*)(Bt + (size_t)(n0 + r) * 256 + k0 + c8);
        }
        __syncthreads();
        bf16x8 af[4], bfv[4];
        #pragma unroll
        for (int mi = 0; mi < 4; ++mi)
            af[mi] = *(const bf16x8*)&As[(wr * 64 + mi * 16 + lm) * 40 + quad * 8];
        #pragma unroll
        for (int ni = 0; ni < 4; ++ni)
            bfv[ni] = *(const bf16x8*)&Bs[(wc * 64 + ni * 16 + lm) * 40 + quad * 8];
        #pragma unroll
        for (int mi = 0; mi < 4; ++mi)
            #pragma unroll
            for (int ni = 0; ni < 4; ++ni)
                acc[mi][ni] = __builtin_amdgcn_mfma_f32_16x16x32_bf16(
                    af[mi], bfv[ni], acc[mi][ni], 0, 0, 0);
        __syncthreads();
    }

    const int type = n0 >> 8;        // 0=q 1=k 2=v
    const int cb = n0 & 255;
    #pragma unroll
    for (int mi = 0; mi < 4; ++mi) {
        #pragma unroll
        for (int j = 0; j < 4; ++j) {
            int m = m0 + wr * 64 + mi * 16 + quad * 4 + j;
            #pragma unroll
            for (int ni = 0; ni < 4; ++ni) {
                int nl = wc * 64 + ni * 16 + lm;
                float val = acc[mi][ni][j] + bias[n0 + nl];
                size_t off = (size_t)m * 256 + cb + nl;
                if (type == 0) qb[off] = (u16)f2bf(val);
                else if (type == 1) kb8[off] = f2fp8(val);
                else {
                    float hx = val * EXPN1;
                    h8[off] = f2fp8(hx);
                    gb[off] = (u16)f2bf(hx);
                }
            }
        }
    }
}

// ---------------- edge scores + softmax (no-max, single pass): one wave per node ----
// lane = (edge_in_chunk<<3) | head. attn16 <- bf16 unnormalized exp; inv <- 1/den.
__global__ __launch_bounds__(256) void edge_softmax_kernel(
        const unsigned* __restrict__ qb, const u8* __restrict__ kb8,
        const int* __restrict__ offs, const int* __restrict__ srcs,
        const float* __restrict__ amask, u16* __restrict__ attn16,
        float* __restrict__ inv) {
    const int wave = threadIdx.x >> 6, lane = threadIdx.x & 63;
    const int node = blockIdx.x * 4 + wave;
    const int h = lane & 7;
    const int eo = lane >> 3;
    const int beg = offs[node], end = offs[node + 1];
    // q row (head h) of this node: 32 bf16 = 16 dwords, streamed once -> NT
    const u32x4* qp = (const u32x4*)(qb + (size_t)node * 128 + h * 16);
    u32x4 q0 = __builtin_nontemporal_load(qp);
    u32x4 q1 = __builtin_nontemporal_load(qp + 1);
    u32x4 q2 = __builtin_nontemporal_load(qp + 2);
    u32x4 q3 = __builtin_nontemporal_load(qp + 3);
    unsigned qq[16] = {q0.x, q0.y, q0.z, q0.w, q1.x, q1.y, q1.z, q1.w,
                       q2.x, q2.y, q2.z, q2.w, q3.x, q3.y, q3.z, q3.w};
    const bool dvalid = amask[node] >= 0.0f;

    float den = 0.0f;
    for (int i0 = beg; i0 < end; i0 += 8) {
        int i = i0 + eo;
        if (i < end) {
            int s = srcs[i];
            const uint4* kp = (const uint4*)(kb8 + (size_t)s * 256 + h * 32);
            uint4 k0 = kp[0], k1 = kp[1];
            unsigned kk[8] = {k0.x, k0.y, k0.z, k0.w, k1.x, k1.y, k1.z, k1.w};
            float acc = 0.0f;
            #pragma unroll
            for (int t = 0; t < 8; ++t) {
                f32x2 a = __builtin_amdgcn_cvt_pk_f32_fp8(kk[t], false);
                f32x2 b = __builtin_amdgcn_cvt_pk_f32_fp8(kk[t], true);
                acc += a.x * bf_lo(qq[2 * t]) + a.y * bf_hi(qq[2 * t]);
                acc += b.x * bf_lo(qq[2 * t + 1]) + b.y * bf_hi(qq[2 * t + 1]);
            }
            bool valid = dvalid && (amask[s] >= 0.0f);
            // scores are tiny (|s|<~1): exp without max-shift is safe
            float es = valid ? __expf(acc) : 0.0f;
            __builtin_nontemporal_store((u16)f2bf(es), &attn16[(size_t)i * 8 + h]);
            den += es;
        }
    }
    den += __shfl_xor(den, 8);
    den += __shfl_xor(den, 16);
    den += __shfl_xor(den, 32);
    if (lane < 8) inv[node * 8 + lane] = (den > 0.0f) ? 1.0f / den : 0.0f;
}

// ---------------- diffuse pass (unnormalized attn, iv folded at end) ----------------
// one wave per node, 4 channels/thread; gb += fact * (iv * sum attn*h[src])
__global__ __launch_bounds__(256) void diffuse_kernel(
        const int* __restrict__ offs, const int* __restrict__ srcs,
        const u16* __restrict__ attn16, const float* __restrict__ inv,
        const unsigned* __restrict__ hcur, unsigned* __restrict__ hnext,
        u32x2* __restrict__ gb, float fact) {
    int gid = blockIdx.x * 256 + threadIdx.x;
    int node = gid >> 6;
    int j2 = gid & 63;
    int h = j2 >> 3;
    int beg = offs[node], end = offs[node + 1];
    float a0 = 0.0f, a1 = 0.0f, a2 = 0.0f, a3 = 0.0f;
    for (int i0 = beg; i0 < end; i0 += 8) {
        int cnt = end - i0; if (cnt > 8) cnt = 8;
        int sarr[8]; float aarr[8]; unsigned hv[8];
        #pragma unroll
        for (int t = 0; t < 8; ++t) if (t < cnt) {
            sarr[t] = srcs[i0 + t];
            aarr[t] = bf16u(__builtin_nontemporal_load(&attn16[(size_t)(i0 + t) * 8 + h]));
        }
        #pragma unroll
        for (int t = 0; t < 8; ++t) if (t < cnt) hv[t] = hcur[(size_t)sarr[t] * 64 + j2];
        #pragma unroll
        for (int t = 0; t < 8; ++t) if (t < cnt) {
            float a = aarr[t];
            f32x2 lo = __builtin_amdgcn_cvt_pk_f32_fp8(hv[t], false);
            f32x2 hi = __builtin_amdgcn_cvt_pk_f32_fp8(hv[t], true);
            a0 += a * lo.x; a1 += a * lo.y;
            a2 += a * hi.x; a3 += a * hi.y;
        }
    }
    float iv = inv[node * 8 + h];
    a0 *= iv; a1 *= iv; a2 *= iv; a3 *= iv;    // normalized h_next
    if (hnext) {
        int pk = __builtin_amdgcn_cvt_pk_fp8_f32(a0, a1, 0, false);
        pk = __builtin_amdgcn_cvt_pk_fp8_f32(a2, a3, pk, true);
        hnext[(size_t)node * 64 + j2] = (unsigned)pk;    // cached: gathered next pass
    }
    u32x2* gp = gb + (size_t)node * 64 + j2;
    u32x2 g = __builtin_nontemporal_load(gp);
    u32x2 ng;
    ng.x = pack2bf(bf_lo(g.x) + fact * a0, bf_hi(g.x) + fact * a1);
    ng.y = pack2bf(bf_lo(g.y) + fact * a2, bf_hi(g.y) + fact * a3);
    if (hnext) __builtin_nontemporal_store(ng, gp);
    else *gp = ng;                                       // last pass: keep for gemm2
}

// ---------------- GEMM2 (64x256 tile) + residual + fused LayerNorm ----------------
__global__ __launch_bounds__(256) void gemm2_ln_kernel(
        const u16* __restrict__ Ab, const u16* __restrict__ Bt,
        const float* __restrict__ bias, const float* __restrict__ resid,
        const float* __restrict__ gamma, const float* __restrict__ beta,
        float* __restrict__ out) {
    __shared__ u16 As[64 * 40];
    __shared__ u16 Bs[256 * 40];
    const int tid = threadIdx.x;
    const int m0 = blockIdx.x * 64;
    const int wave = tid >> 6, lane = tid & 63;
    const int lm = lane & 15, quad = lane >> 4;

    f32x4 acc[16] = {};
    for (int k0 = 0; k0 < 256; k0 += 32) {
        *(uint4*)&As[(tid >> 2) * 40 + (tid & 3) * 8] =
            *(const uint4*)(Ab + (size_t)(m0 + (tid >> 2)) * 256 + k0 + (tid & 3) * 8);
        {
            const uint4* srcp = (const uint4*)(Bt + (size_t)tid * 256 + k0);
            uint4* dstp = (uint4*)&Bs[tid * 40];
            dstp[0] = srcp[0]; dstp[1] = srcp[1]; dstp[2] = srcp[2]; dstp[3] = srcp[3];
        }
        __syncthreads();
        bf16x8 af = *(const bf16x8*)&As[(wave * 16 + lm) * 40 + quad * 8];
        #pragma unroll
        for (int ni = 0; ni < 16; ++ni) {
            bf16x8 bfv = *(const bf16x8*)&Bs[(ni * 16 + lm) * 40 + quad * 8];
            acc[ni] = __builtin_amdgcn_mfma_f32_16x16x32_bf16(af, bfv, acc[ni], 0, 0, 0);
        }
        __syncthreads();
    }

    const int mrow = m0 + wave * 16 + quad * 4;
    float ga[16], be[16];
    float rowsum[4] = {}, rowsq[4] = {};
    #pragma unroll
    for (int ni = 0; ni < 16; ++ni) {
        int col = ni * 16 + lm;
        float bia = bias[col];
        ga[ni] = gamma[col]; be[ni] = beta[col];
        #pragma unroll
        for (int j = 0; j < 4; ++j) {
            float val = acc[ni][j] + bia +
                        __builtin_nontemporal_load(&resid[(size_t)(mrow + j) * 256 + col]);
            acc[ni][j] = val;
            rowsum[j] += val;
            rowsq[j] += val * val;
        }
    }
    #pragma unroll
    for (int j = 0; j < 4; ++j) {
        #pragma unroll
        for (int msk = 1; msk <= 8; msk <<= 1) {
            rowsum[j] += __shfl_xor(rowsum[j], msk);
            rowsq[j] += __shfl_xor(rowsq[j], msk);
        }
    }
    float mu[4], rstd[4];
    #pragma unroll
    for (int j = 0; j < 4; ++j) {
        mu[j] = rowsum[j] * (1.0f / 256.0f);
        float var = rowsq[j] * (1.0f / 256.0f) - mu[j] * mu[j];
        rstd[j] = 1.0f / sqrtf(var + LN_EPS);
    }
    #pragma unroll
    for (int ni = 0; ni < 16; ++ni) {
        int col = ni * 16 + lm;
        #pragma unroll
        for (int j = 0; j < 4; ++j)
            __builtin_nontemporal_store(
                (acc[ni][j] - mu[j]) * rstd[j] * ga[ni] + be[ni],
                &out[(size_t)(mrow + j) * 256 + col]);
    }
}

extern "C" void kernel_launch(void* const* d_in, const int* in_sizes, int n_in,
                              void* d_out, int out_size, void* d_ws, size_t ws_size,
                              hipStream_t stream) {
    const float* hidden = (const float*)d_in[0];
    const float* amask  = (const float*)d_in[1];
    const int*   src    = (const int*)d_in[2];
    const int*   dst    = (const int*)d_in[3];
    const float* Wqkv   = (const float*)d_in[4];
    const float* bqkv   = (const float*)d_in[5];
    const float* Wo     = (const float*)d_in[6];
    const float* bo     = (const float*)d_in[7];
    const float* gamma  = (const float*)d_in[8];
    const float* beta   = (const float*)d_in[9];
    float* out = (float*)d_out;

    char* p = (char*)d_ws;
    u16*      hidb   = (u16*)p;      p += (size_t)NN * DD * 2;     // 8 MB
    u16*      WtQ    = (u16*)p;      p += (size_t)D3 * DD * 2;
    u16*      WtO    = (u16*)p;      p += (size_t)DD * DD * 2;
    float*    biasq  = (float*)p;    p += (size_t)D3 * 4;
    float*    biaso  = (float*)p;    p += (size_t)DD * 4;
    u16*      qb     = (u16*)p;      p += (size_t)NN * DD * 2;     // 8 MB bf16
    u8*       kb8    = (u8*)p;       p += (size_t)NN * DD;         // 4 MB fp8
    u8*       h8A    = (u8*)p;       p += (size_t)NN * DD;         // 4 MB fp8
    u8*       h8B    = (u8*)p;       p += (size_t)NN * DD;         // 4 MB fp8
    u16*      gb     = (u16*)p;      p += (size_t)NN * DD * 2;     // 8 MB bf16 gather acc
    u16*      attn16 = (u16*)p;      p += (size_t)EE * HH * 2;     // 4 MB bf16 unnorm exp
    float*    inv    = (float*)p;    p += (size_t)NN * HH * 4;     // 0.5 MB
    int*      deg    = (int*)p;      p += (size_t)NN * 4;
    int*      offs   = (int*)p;      p += (size_t)(NN + 1) * 4;
    int*      cursor = (int*)p;      p += (size_t)NN * 4;
    int*      srcs   = (int*)p;      p += (size_t)EE * 4;

    // 1. zero degree histogram, then fused prep (convs + hist)
    hipMemsetAsync(deg, 0, (size_t)NN * 4, stream);
    prep_kernel<<<6144, 256, 0, stream>>>(hidden, (unsigned*)hidb,
                                          Wqkv, bqkv, WtQ, biasq,
                                          Wo, bo, WtO, biaso, dst, deg);

    // 2. CSR scan
    scan_kernel<<<1, 1024, 0, stream>>>(deg, offs, cursor, NN);

    // 3. QKV projection (MFMA, blocks 0..767) || CSR scatter (blocks 768..1791)
    gemm1_scatter_kernel<<<1792, 256, 0, stream>>>(
        hidb, WtQ, biasq, qb, kb8, h8A, gb, src, dst, cursor, srcs);

    // 4. edge scores + softmax (single pass, bf16 unnorm exp + inv)
    edge_softmax_kernel<<<NN / 4, 256, 0, stream>>>(
        (const unsigned*)qb, kb8, offs, srcs, amask, attn16, inv);

    // 5. diffusion: gb = h0 + h1 + h2/2 + h3/6
    diffuse_kernel<<<(NN * 64) / 256, 256, 0, stream>>>(
        offs, srcs, attn16, inv, (const unsigned*)h8A, (unsigned*)h8B, (u32x2*)gb, 1.0f);
    diffuse_kernel<<<(NN * 64) / 256, 256, 0, stream>>>(
        offs, srcs, attn16, inv, (const unsigned*)h8B, (unsigned*)h8A, (u32x2*)gb, 0.5f);
    diffuse_kernel<<<(NN * 64) / 256, 256, 0, stream>>>(
        offs, srcs, attn16, inv, (const unsigned*)h8A, nullptr, (u32x2*)gb, 1.0f / 6.0f);

    // 6. output projection + residual + fused LayerNorm -> out
    gemm2_ln_kernel<<<NN / 64, 256, 0, stream>>>(
        gb, WtO, biaso, hidden, gamma, beta, out);
}

// Round 10
// 286.487 us; speedup vs baseline: 1.0192x; 1.0192x over previous
//
#include <hip/hip_runtime.h>
#include <math.h>

#define NN 16384      // B*S nodes
#define DD 256        // model dim
#define HH 8          // heads
#define EE 262144     // edges
#define D3 768        // 3*D
#define QSCALE 0.17677669529663687f   // 1/sqrt(32)
#define EXPN1 0.36787944117144233f    // exp(-1)
#define LN_EPS 1e-12f

typedef short bf16x8 __attribute__((ext_vector_type(8)));
typedef float f32x4 __attribute__((ext_vector_type(4)));
typedef float f32x2 __attribute__((ext_vector_type(2)));
typedef unsigned short u16;
typedef unsigned char u8;

// ---- bf16 helpers ----
__device__ __forceinline__ float bf_lo(unsigned u) { return __uint_as_float(u << 16); }
__device__ __forceinline__ float bf_hi(unsigned u) { return __uint_as_float(u & 0xffff0000u); }
__device__ __forceinline__ float bf16u(u16 u) { return __uint_as_float(((unsigned)u) << 16); }
__device__ __forceinline__ unsigned f2bf(float f) {  // RNE
    unsigned b = __float_as_uint(f);
    return (b + 0x7fffu + ((b >> 16) & 1u)) >> 16;
}
__device__ __forceinline__ unsigned pack2bf(float lo, float hi) {
    return f2bf(lo) | (f2bf(hi) << 16);
}
// ---- fp8 e4m3 helpers (HW cvt) ----
__device__ __forceinline__ u8 f2fp8(float v) {
    return (u8)(__builtin_amdgcn_cvt_pk_fp8_f32(v, v, 0, false) & 0xff);
}

// ---------------- prep: hconv (4096 blk) + wconvQ (768) + wconvO (256) + hist (1024) ----
__global__ void prep_kernel(const float* __restrict__ hidden, unsigned* __restrict__ hidb,
                            const float* __restrict__ Wqkv, const float* __restrict__ bqkv,
                            u16* __restrict__ WtQ, float* __restrict__ biasq,
                            const float* __restrict__ Wo, const float* __restrict__ bo,
                            u16* __restrict__ WtO, float* __restrict__ biaso,
                            const int* __restrict__ dst, int* __restrict__ deg) {
    int b = blockIdx.x;
    if (b < 4096) {
        int gid = b * 256 + threadIdx.x;
        float4 v = *(const float4*)(hidden + (size_t)gid * 4);
        *(uint2*)(hidb + (size_t)gid * 2) = make_uint2(pack2bf(v.x, v.y), pack2bf(v.z, v.w));
    } else if (b < 4864) {
        int gid = (b - 4096) * 256 + threadIdx.x;
        int n = gid >> 8, k = gid & 255;
        float s = (n < DD) ? QSCALE : 1.0f;
        WtQ[(size_t)n * 256 + k] = (u16)f2bf(Wqkv[(size_t)k * D3 + n] * s);
        if (k == 0) biasq[n] = bqkv[n] * s;
    } else if (b < 5120) {
        int gid = (b - 4864) * 256 + threadIdx.x;
        int n = gid >> 8, k = gid & 255;
        WtO[(size_t)n * 256 + k] = (u16)f2bf(Wo[(size_t)k * DD + n]);
        if (k == 0) biaso[n] = bo[n];
    } else {
        int e = (b - 5120) * 256 + threadIdx.x;
        atomicAdd(&deg[dst[e]], 1);
    }
}

// ---------------- scan (single block, 1024 threads, 16 nodes each) ----------------
__global__ __launch_bounds__(1024) void scan_kernel(const int* __restrict__ deg,
                                                    int* __restrict__ offs,
                                                    int* __restrict__ cursor, int n) {
    __shared__ int part[1024];
    int t = threadIdx.x;
    int base = t * 16;
    int local[16];
    int s = 0;
    #pragma unroll
    for (int i = 0; i < 16; ++i) { local[i] = s; s += deg[base + i]; }
    part[t] = s;
    __syncthreads();
    for (int d = 1; d < 1024; d <<= 1) {
        int add = (t >= d) ? part[t - d] : 0;
        __syncthreads();
        part[t] += add;
        __syncthreads();
    }
    int excl = part[t] - s;
    #pragma unroll
    for (int i = 0; i < 16; ++i) {
        offs[base + i] = excl + local[i];
        cursor[base + i] = excl + local[i];
    }
    if (t == 1023) offs[n] = excl + s;
}

// ---------------- fused: gemm1 (blocks 0..767) + scatter (blocks 768..1791) ----------------
__global__ __launch_bounds__(256) void gemm1_scatter_kernel(
        const u16* __restrict__ Ab, const u16* __restrict__ Bt,
        const float* __restrict__ bias,
        u16* __restrict__ qb, u8* __restrict__ kb8,
        u8* __restrict__ h8, u16* __restrict__ gb,
        const int* __restrict__ src, const int* __restrict__ dst,
        int* __restrict__ cursor, int* __restrict__ srcs) {
    __shared__ u16 As[128 * 40];
    __shared__ u16 Bs[128 * 40];
    const int tid = threadIdx.x;
    if (blockIdx.x >= 768) {                  // ---- scatter role ----
        int e = (blockIdx.x - 768) * 256 + tid;
        int pos = atomicAdd(&cursor[dst[e]], 1);
        srcs[pos] = src[e];
        return;
    }
    // ---- gemm1 role ----
    const int n0 = (blockIdx.x % 6) * 128;
    const int m0 = (blockIdx.x / 6) * 128;
    const int wave = tid >> 6, lane = tid & 63;
    const int wr = wave >> 1, wc = wave & 1;
    const int lm = lane & 15, quad = lane >> 4;

    f32x4 acc[4][4] = {};
    const int r0 = tid >> 2;
    const int c8 = (tid & 3) * 8;

    for (int k0 = 0; k0 < 256; k0 += 32) {
        #pragma unroll
        for (int s = 0; s < 2; ++s) {
            int r = r0 + s * 64;
            *(uint4*)&As[r * 40 + c8] = *(const uint4*)(Ab + (size_t)(m0 + r) * 256 + k0 + c8);
            *(uint4*)&Bs[r * 40 + c8] = *(const uint4*)(Bt + (size_t)(n0 + r) * 256 + k0 + c8);
        }
        __syncthreads();
        bf16x8 af[4], bfv[4];
        #pragma unroll
        for (int mi = 0; mi < 4; ++mi)
            af[mi] = *(const bf16x8*)&As[(wr * 64 + mi * 16 + lm) * 40 + quad * 8];
        #pragma unroll
        for (int ni = 0; ni < 4; ++ni)
            bfv[ni] = *(const bf16x8*)&Bs[(wc * 64 + ni * 16 + lm) * 40 + quad * 8];
        #pragma unroll
        for (int mi = 0; mi < 4; ++mi)
            #pragma unroll
            for (int ni = 0; ni < 4; ++ni)
                acc[mi][ni] = __builtin_amdgcn_mfma_f32_16x16x32_bf16(
                    af[mi], bfv[ni], acc[mi][ni], 0, 0, 0);
        __syncthreads();
    }

    const int type = n0 >> 8;        // 0=q 1=k 2=v
    const int cb = n0 & 255;
    #pragma unroll
    for (int mi = 0; mi < 4; ++mi) {
        #pragma unroll
        for (int j = 0; j < 4; ++j) {
            int m = m0 + wr * 64 + mi * 16 + quad * 4 + j;
            #pragma unroll
            for (int ni = 0; ni < 4; ++ni) {
                int nl = wc * 64 + ni * 16 + lm;
                float val = acc[mi][ni][j] + bias[n0 + nl];
                size_t off = (size_t)m * 256 + cb + nl;
                if (type == 0) qb[off] = (u16)f2bf(val);
                else if (type == 1) kb8[off] = f2fp8(val);
                else {
                    float hx = val * EXPN1;
                    h8[off] = f2fp8(hx);
                    gb[off] = (u16)f2bf(hx);
                }
            }
        }
    }
}

// ---------------- edge scores + softmax (no-max, single pass): one wave per node ----
// lane = (edge_in_chunk<<3) | head. attn16 <- bf16 unnormalized exp; inv <- 1/den.
__global__ __launch_bounds__(256) void edge_softmax_kernel(
        const unsigned* __restrict__ qb, const u8* __restrict__ kb8,
        const int* __restrict__ offs, const int* __restrict__ srcs,
        const float* __restrict__ amask, u16* __restrict__ attn16,
        float* __restrict__ inv) {
    const int wave = threadIdx.x >> 6, lane = threadIdx.x & 63;
    const int node = blockIdx.x * 4 + wave;
    const int h = lane & 7;
    const int eo = lane >> 3;
    const int beg = offs[node], end = offs[node + 1];
    const uint4* qp = (const uint4*)(qb + (size_t)node * 128 + h * 16);
    uint4 q0 = qp[0], q1 = qp[1], q2 = qp[2], q3 = qp[3];
    unsigned qq[16] = {q0.x, q0.y, q0.z, q0.w, q1.x, q1.y, q1.z, q1.w,
                       q2.x, q2.y, q2.z, q2.w, q3.x, q3.y, q3.z, q3.w};
    const bool dvalid = amask[node] >= 0.0f;

    float den = 0.0f;
    for (int i0 = beg; i0 < end; i0 += 8) {
        int i = i0 + eo;
        if (i < end) {
            int s = srcs[i];
            const uint4* kp = (const uint4*)(kb8 + (size_t)s * 256 + h * 32);
            uint4 k0 = kp[0], k1 = kp[1];
            unsigned kk[8] = {k0.x, k0.y, k0.z, k0.w, k1.x, k1.y, k1.z, k1.w};
            float acc = 0.0f;
            #pragma unroll
            for (int t = 0; t < 8; ++t) {
                f32x2 a = __builtin_amdgcn_cvt_pk_f32_fp8(kk[t], false);
                f32x2 b = __builtin_amdgcn_cvt_pk_f32_fp8(kk[t], true);
                acc += a.x * bf_lo(qq[2 * t]) + a.y * bf_hi(qq[2 * t]);
                acc += b.x * bf_lo(qq[2 * t + 1]) + b.y * bf_hi(qq[2 * t + 1]);
            }
            bool valid = dvalid && (amask[s] >= 0.0f);
            // scores are tiny (|s|<~1): exp without max-shift is safe
            float es = valid ? __expf(acc) : 0.0f;
            attn16[(size_t)i * 8 + h] = (u16)f2bf(es);
            den += es;
        }
    }
    den += __shfl_xor(den, 8);
    den += __shfl_xor(den, 16);
    den += __shfl_xor(den, 32);
    if (lane < 8) inv[node * 8 + lane] = (den > 0.0f) ? 1.0f / den : 0.0f;
}

// ---------------- diffuse pass: one wave/node, 4 ch/thread, 16-edge MLP batches ----
__global__ __launch_bounds__(256) void diffuse_kernel(
        const int* __restrict__ offs, const int* __restrict__ srcs,
        const u16* __restrict__ attn16, const float* __restrict__ inv,
        const unsigned* __restrict__ hcur, unsigned* __restrict__ hnext,
        uint2* __restrict__ gb, float fact) {
    int gid = blockIdx.x * 256 + threadIdx.x;
    int node = gid >> 6;
    int j2 = gid & 63;
    int h = j2 >> 3;
    int beg = offs[node], end = offs[node + 1];
    float a0 = 0.0f, a1 = 0.0f, a2 = 0.0f, a3 = 0.0f;
    for (int i0 = beg; i0 < end; i0 += 16) {
        int cnt = end - i0; if (cnt > 16) cnt = 16;
        int sarr[16]; float aarr[16]; unsigned hv[16];
        #pragma unroll
        for (int t = 0; t < 16; ++t) if (t < cnt) {
            sarr[t] = srcs[i0 + t];
            aarr[t] = bf16u(attn16[(size_t)(i0 + t) * 8 + h]);
        }
        #pragma unroll
        for (int t = 0; t < 16; ++t) if (t < cnt) hv[t] = hcur[(size_t)sarr[t] * 64 + j2];
        #pragma unroll
        for (int t = 0; t < 16; ++t) if (t < cnt) {
            float a = aarr[t];
            f32x2 lo = __builtin_amdgcn_cvt_pk_f32_fp8(hv[t], false);
            f32x2 hi = __builtin_amdgcn_cvt_pk_f32_fp8(hv[t], true);
            a0 += a * lo.x; a1 += a * lo.y;
            a2 += a * hi.x; a3 += a * hi.y;
        }
    }
    float iv = inv[node * 8 + h];
    a0 *= iv; a1 *= iv; a2 *= iv; a3 *= iv;    // normalized h_next contribution
    if (hnext) {
        int pk = __builtin_amdgcn_cvt_pk_fp8_f32(a0, a1, 0, false);
        pk = __builtin_amdgcn_cvt_pk_fp8_f32(a2, a3, pk, true);
        hnext[(size_t)node * 64 + j2] = (unsigned)pk;
    }
    uint2* gp = gb + (size_t)node * 64 + j2;
    uint2 g = *gp;
    *gp = make_uint2(pack2bf(bf_lo(g.x) + fact * a0, bf_hi(g.x) + fact * a1),
                     pack2bf(bf_lo(g.y) + fact * a2, bf_hi(g.y) + fact * a3));
}

// ---------------- GEMM2 (64x256 tile) + residual + fused LayerNorm ----------------
__global__ __launch_bounds__(256) void gemm2_ln_kernel(
        const u16* __restrict__ Ab, const u16* __restrict__ Bt,
        const float* __restrict__ bias, const float* __restrict__ resid,
        const float* __restrict__ gamma, const float* __restrict__ beta,
        float* __restrict__ out) {
    __shared__ u16 As[64 * 40];
    __shared__ u16 Bs[256 * 40];
    const int tid = threadIdx.x;
    const int m0 = blockIdx.x * 64;
    const int wave = tid >> 6, lane = tid & 63;
    const int lm = lane & 15, quad = lane >> 4;

    f32x4 acc[16] = {};
    for (int k0 = 0; k0 < 256; k0 += 32) {
        *(uint4*)&As[(tid >> 2) * 40 + (tid & 3) * 8] =
            *(const uint4*)(Ab + (size_t)(m0 + (tid >> 2)) * 256 + k0 + (tid & 3) * 8);
        {
            const uint4* srcp = (const uint4*)(Bt + (size_t)tid * 256 + k0);
            uint4* dstp = (uint4*)&Bs[tid * 40];
            dstp[0] = srcp[0]; dstp[1] = srcp[1]; dstp[2] = srcp[2]; dstp[3] = srcp[3];
        }
        __syncthreads();
        bf16x8 af = *(const bf16x8*)&As[(wave * 16 + lm) * 40 + quad * 8];
        #pragma unroll
        for (int ni = 0; ni < 16; ++ni) {
            bf16x8 bfv = *(const bf16x8*)&Bs[(ni * 16 + lm) * 40 + quad * 8];
            acc[ni] = __builtin_amdgcn_mfma_f32_16x16x32_bf16(af, bfv, acc[ni], 0, 0, 0);
        }
        __syncthreads();
    }

    const int mrow = m0 + wave * 16 + quad * 4;
    float ga[16], be[16];
    float rowsum[4] = {}, rowsq[4] = {};
    #pragma unroll
    for (int ni = 0; ni < 16; ++ni) {
        int col = ni * 16 + lm;
        float bia = bias[col];
        ga[ni] = gamma[col]; be[ni] = beta[col];
        #pragma unroll
        for (int j = 0; j < 4; ++j) {
            float val = acc[ni][j] + bia +
                        __builtin_nontemporal_load(&resid[(size_t)(mrow + j) * 256 + col]);
            acc[ni][j] = val;
            rowsum[j] += val;
            rowsq[j] += val * val;
        }
    }
    #pragma unroll
    for (int j = 0; j < 4; ++j) {
        #pragma unroll
        for (int msk = 1; msk <= 8; msk <<= 1) {
            rowsum[j] += __shfl_xor(rowsum[j], msk);
            rowsq[j] += __shfl_xor(rowsq[j], msk);
        }
    }
    float mu[4], rstd[4];
    #pragma unroll
    for (int j = 0; j < 4; ++j) {
        mu[j] = rowsum[j] * (1.0f / 256.0f);
        float var = rowsq[j] * (1.0f / 256.0f) - mu[j] * mu[j];
        rstd[j] = 1.0f / sqrtf(var + LN_EPS);
    }
    #pragma unroll
    for (int ni = 0; ni < 16; ++ni) {
        int col = ni * 16 + lm;
        #pragma unroll
        for (int j = 0; j < 4; ++j)
            __builtin_nontemporal_store(
                (acc[ni][j] - mu[j]) * rstd[j] * ga[ni] + be[ni],
                &out[(size_t)(mrow + j) * 256 + col]);
    }
}

extern "C" void kernel_launch(void* const* d_in, const int* in_sizes, int n_in,
                              void* d_out, int out_size, void* d_ws, size_t ws_size,
                              hipStream_t stream) {
    const float* hidden = (const float*)d_in[0];
    const float* amask  = (const float*)d_in[1];
    const int*   src    = (const int*)d_in[2];
    const int*   dst    = (const int*)d_in[3];
    const float* Wqkv   = (const float*)d_in[4];
    const float* bqkv   = (const float*)d_in[5];
    const float* Wo     = (const float*)d_in[6];
    const float* bo     = (const float*)d_in[7];
    const float* gamma  = (const float*)d_in[8];
    const float* beta   = (const float*)d_in[9];
    float* out = (float*)d_out;

    char* p = (char*)d_ws;
    u16*      hidb   = (u16*)p;      p += (size_t)NN * DD * 2;     // 8 MB
    u16*      WtQ    = (u16*)p;      p += (size_t)D3 * DD * 2;
    u16*      WtO    = (u16*)p;      p += (size_t)DD * DD * 2;
    float*    biasq  = (float*)p;    p += (size_t)D3 * 4;
    float*    biaso  = (float*)p;    p += (size_t)DD * 4;
    u16*      qb     = (u16*)p;      p += (size_t)NN * DD * 2;     // 8 MB bf16
    u8*       kb8    = (u8*)p;       p += (size_t)NN * DD;         // 4 MB fp8
    u8*       h8A    = (u8*)p;       p += (size_t)NN * DD;         // 4 MB fp8
    u8*       h8B    = (u8*)p;       p += (size_t)NN * DD;         // 4 MB fp8
    u16*      gb     = (u16*)p;      p += (size_t)NN * DD * 2;     // 8 MB bf16 gather acc
    u16*      attn16 = (u16*)p;      p += (size_t)EE * HH * 2;     // 4 MB bf16 unnorm exp
    float*    inv    = (float*)p;    p += (size_t)NN * HH * 4;     // 0.5 MB
    int*      deg    = (int*)p;      p += (size_t)NN * 4;
    int*      offs   = (int*)p;      p += (size_t)(NN + 1) * 4;
    int*      cursor = (int*)p;      p += (size_t)NN * 4;
    int*      srcs   = (int*)p;      p += (size_t)EE * 4;

    // 1. zero degree histogram, then fused prep (convs + hist)
    hipMemsetAsync(deg, 0, (size_t)NN * 4, stream);
    prep_kernel<<<6144, 256, 0, stream>>>(hidden, (unsigned*)hidb,
                                          Wqkv, bqkv, WtQ, biasq,
                                          Wo, bo, WtO, biaso, dst, deg);

    // 2. CSR scan
    scan_kernel<<<1, 1024, 0, stream>>>(deg, offs, cursor, NN);

    // 3. QKV projection (MFMA, blocks 0..767) || CSR scatter (blocks 768..1791)
    gemm1_scatter_kernel<<<1792, 256, 0, stream>>>(
        hidb, WtQ, biasq, qb, kb8, h8A, gb, src, dst, cursor, srcs);

    // 4. edge scores + softmax (single pass, bf16 unnorm exp + inv)
    edge_softmax_kernel<<<NN / 4, 256, 0, stream>>>(
        (const unsigned*)qb, kb8, offs, srcs, amask, attn16, inv);

    // 5. diffusion: gb = h0 + h1 + h2/2 + h3/6
    diffuse_kernel<<<(NN * 64) / 256, 256, 0, stream>>>(
        offs, srcs, attn16, inv, (const unsigned*)h8A, (unsigned*)h8B, (uint2*)gb, 1.0f);
    diffuse_kernel<<<(NN * 64) / 256, 256, 0, stream>>>(
        offs, srcs, attn16, inv, (const unsigned*)h8B, (unsigned*)h8A, (uint2*)gb, 0.5f);
    diffuse_kernel<<<(NN * 64) / 256, 256, 0, stream>>>(
        offs, srcs, attn16, inv, (const unsigned*)h8A, nullptr, (uint2*)gb, 1.0f / 6.0f);

    // 6. output projection + residual + fused LayerNorm -> out
    gemm2_ln_kernel<<<NN / 64, 256, 0, stream>>>(
        gb, WtO, biaso, hidden, gamma, beta, out);
}

// Round 11
// 226.044 us; speedup vs baseline: 1.2917x; 1.2674x over previous
//
#include <hip/hip_runtime.h>
#include <math.h>

#define NN 16384      // B*S nodes
#define DD 256        // model dim
#define HH 8          // heads
#define EE 262144     // edges
#define D3 768        // 3*D
#define QSCALE 0.17677669529663687f   // 1/sqrt(32)
#define EXPN1 0.36787944117144233f    // exp(-1)
#define LN_EPS 1e-12f

typedef short bf16x8 __attribute__((ext_vector_type(8)));
typedef float f32x4 __attribute__((ext_vector_type(4)));
typedef float f32x2 __attribute__((ext_vector_type(2)));
typedef unsigned short u16;
typedef unsigned char u8;

// ---- bf16 helpers ----
__device__ __forceinline__ float bf_lo(unsigned u) { return __uint_as_float(u << 16); }
__device__ __forceinline__ float bf_hi(unsigned u) { return __uint_as_float(u & 0xffff0000u); }
__device__ __forceinline__ float bf16u(u16 u) { return __uint_as_float(((unsigned)u) << 16); }
__device__ __forceinline__ unsigned f2bf(float f) {  // RNE
    unsigned b = __float_as_uint(f);
    return (b + 0x7fffu + ((b >> 16) & 1u)) >> 16;
}
__device__ __forceinline__ unsigned pack2bf(float lo, float hi) {
    return f2bf(lo) | (f2bf(hi) << 16);
}
// ---- fp8 e4m3 helpers (HW cvt) ----
__device__ __forceinline__ u8 f2fp8(float v) {
    return (u8)(__builtin_amdgcn_cvt_pk_fp8_f32(v, v, 0, false) & 0xff);
}

// ---------------- prep: hconv (4096 blk) + wconvQ (768) + wconvO (256) + hist (1024) ----
__global__ void prep_kernel(const float* __restrict__ hidden, unsigned* __restrict__ hidb,
                            const float* __restrict__ Wqkv, const float* __restrict__ bqkv,
                            u16* __restrict__ WtQ, float* __restrict__ biasq,
                            const float* __restrict__ Wo, const float* __restrict__ bo,
                            u16* __restrict__ WtO, float* __restrict__ biaso,
                            const int* __restrict__ dst, int* __restrict__ deg) {
    int b = blockIdx.x;
    if (b < 4096) {
        int gid = b * 256 + threadIdx.x;
        float4 v = *(const float4*)(hidden + (size_t)gid * 4);
        *(uint2*)(hidb + (size_t)gid * 2) = make_uint2(pack2bf(v.x, v.y), pack2bf(v.z, v.w));
    } else if (b < 4864) {
        int gid = (b - 4096) * 256 + threadIdx.x;
        int n = gid >> 8, k = gid & 255;
        float s = (n < DD) ? QSCALE : 1.0f;
        WtQ[(size_t)n * 256 + k] = (u16)f2bf(Wqkv[(size_t)k * D3 + n] * s);
        if (k == 0) biasq[n] = bqkv[n] * s;
    } else if (b < 5120) {
        int gid = (b - 4864) * 256 + threadIdx.x;
        int n = gid >> 8, k = gid & 255;
        WtO[(size_t)n * 256 + k] = (u16)f2bf(Wo[(size_t)k * DD + n]);
        if (k == 0) biaso[n] = bo[n];
    } else {
        int e = (b - 5120) * 256 + threadIdx.x;
        atomicAdd(&deg[dst[e]], 1);
    }
}

// ---------------- scan (single block, 1024 threads, 16 nodes each) ----------------
__global__ __launch_bounds__(1024) void scan_kernel(const int* __restrict__ deg,
                                                    int* __restrict__ offs,
                                                    int* __restrict__ cursor, int n) {
    __shared__ int part[1024];
    int t = threadIdx.x;
    int base = t * 16;
    int local[16];
    int s = 0;
    #pragma unroll
    for (int i = 0; i < 16; ++i) { local[i] = s; s += deg[base + i]; }
    part[t] = s;
    __syncthreads();
    for (int d = 1; d < 1024; d <<= 1) {
        int add = (t >= d) ? part[t - d] : 0;
        __syncthreads();
        part[t] += add;
        __syncthreads();
    }
    int excl = part[t] - s;
    #pragma unroll
    for (int i = 0; i < 16; ++i) {
        offs[base + i] = excl + local[i];
        cursor[base + i] = excl + local[i];
    }
    if (t == 1023) offs[n] = excl + s;
}

// ---------------- fused: gemm1 (blocks 0..767) + scatter (blocks 768..1791) ----------------
__global__ __launch_bounds__(256) void gemm1_scatter_kernel(
        const u16* __restrict__ Ab, const u16* __restrict__ Bt,
        const float* __restrict__ bias,
        u16* __restrict__ qb, u8* __restrict__ kb8,
        u8* __restrict__ h8, u16* __restrict__ gb,
        const int* __restrict__ src, const int* __restrict__ dst,
        int* __restrict__ cursor, int* __restrict__ srcs) {
    __shared__ u16 As[128 * 40];
    __shared__ u16 Bs[128 * 40];
    const int tid = threadIdx.x;
    if (blockIdx.x >= 768) {                  // ---- scatter role ----
        int e = (blockIdx.x - 768) * 256 + tid;
        int pos = atomicAdd(&cursor[dst[e]], 1);
        srcs[pos] = src[e];
        return;
    }
    // ---- gemm1 role ----
    const int n0 = (blockIdx.x % 6) * 128;
    const int m0 = (blockIdx.x / 6) * 128;
    const int wave = tid >> 6, lane = tid & 63;
    const int wr = wave >> 1, wc = wave & 1;
    const int lm = lane & 15, quad = lane >> 4;

    f32x4 acc[4][4] = {};
    const int r0 = tid >> 2;
    const int c8 = (tid & 3) * 8;

    for (int k0 = 0; k0 < 256; k0 += 32) {
        #pragma unroll
        for (int s = 0; s < 2; ++s) {
            int r = r0 + s * 64;
            *(uint4*)&As[r * 40 + c8] = *(const uint4*)(Ab + (size_t)(m0 + r) * 256 + k0 + c8);
            *(uint4*)&Bs[r * 40 + c8] = *(const uint4*)(Bt + (size_t)(n0 + r) * 256 + k0 + c8);
        }
        __syncthreads();
        bf16x8 af[4], bfv[4];
        #pragma unroll
        for (int mi = 0; mi < 4; ++mi)
            af[mi] = *(const bf16x8*)&As[(wr * 64 + mi * 16 + lm) * 40 + quad * 8];
        #pragma unroll
        for (int ni = 0; ni < 4; ++ni)
            bfv[ni] = *(const bf16x8*)&Bs[(wc * 64 + ni * 16 + lm) * 40 + quad * 8];
        #pragma unroll
        for (int mi = 0; mi < 4; ++mi)
            #pragma unroll
            for (int ni = 0; ni < 4; ++ni)
                acc[mi][ni] = __builtin_amdgcn_mfma_f32_16x16x32_bf16(
                    af[mi], bfv[ni], acc[mi][ni], 0, 0, 0);
        __syncthreads();
    }

    const int type = n0 >> 8;        // 0=q 1=k 2=v
    const int cb = n0 & 255;
    #pragma unroll
    for (int mi = 0; mi < 4; ++mi) {
        #pragma unroll
        for (int j = 0; j < 4; ++j) {
            int m = m0 + wr * 64 + mi * 16 + quad * 4 + j;
            #pragma unroll
            for (int ni = 0; ni < 4; ++ni) {
                int nl = wc * 64 + ni * 16 + lm;
                float val = acc[mi][ni][j] + bias[n0 + nl];
                size_t off = (size_t)m * 256 + cb + nl;
                if (type == 0) qb[off] = (u16)f2bf(val);
                else if (type == 1) kb8[off] = f2fp8(val);
                else {
                    float hx = val * EXPN1;
                    h8[off] = f2fp8(hx);
                    gb[off] = (u16)f2bf(hx);
                }
            }
        }
    }
}

// ---------------- edge scores + softmax (no-max, single pass): one wave per node ----
// lane = (edge_in_chunk<<3) | head. attn16 <- bf16 unnormalized exp; inv <- 1/den.
__global__ __launch_bounds__(256) void edge_softmax_kernel(
        const unsigned* __restrict__ qb, const u8* __restrict__ kb8,
        const int* __restrict__ offs, const int* __restrict__ srcs,
        const float* __restrict__ amask, u16* __restrict__ attn16,
        float* __restrict__ inv) {
    const int wave = threadIdx.x >> 6, lane = threadIdx.x & 63;
    const int node = blockIdx.x * 4 + wave;
    const int h = lane & 7;
    const int eo = lane >> 3;
    const int beg = offs[node], end = offs[node + 1];
    const uint4* qp = (const uint4*)(qb + (size_t)node * 128 + h * 16);
    uint4 q0 = qp[0], q1 = qp[1], q2 = qp[2], q3 = qp[3];
    unsigned qq[16] = {q0.x, q0.y, q0.z, q0.w, q1.x, q1.y, q1.z, q1.w,
                       q2.x, q2.y, q2.z, q2.w, q3.x, q3.y, q3.z, q3.w};
    const bool dvalid = amask[node] >= 0.0f;

    float den = 0.0f;
    for (int i0 = beg; i0 < end; i0 += 8) {
        int i = i0 + eo;
        if (i < end) {
            int s = srcs[i];
            const uint4* kp = (const uint4*)(kb8 + (size_t)s * 256 + h * 32);
            uint4 k0 = kp[0], k1 = kp[1];
            unsigned kk[8] = {k0.x, k0.y, k0.z, k0.w, k1.x, k1.y, k1.z, k1.w};
            float acc = 0.0f;
            #pragma unroll
            for (int t = 0; t < 8; ++t) {
                f32x2 a = __builtin_amdgcn_cvt_pk_f32_fp8(kk[t], false);
                f32x2 b = __builtin_amdgcn_cvt_pk_f32_fp8(kk[t], true);
                acc += a.x * bf_lo(qq[2 * t]) + a.y * bf_hi(qq[2 * t]);
                acc += b.x * bf_lo(qq[2 * t + 1]) + b.y * bf_hi(qq[2 * t + 1]);
            }
            bool valid = dvalid && (amask[s] >= 0.0f);
            // scores are tiny (|s|<~1): exp without max-shift is safe
            float es = valid ? __expf(acc) : 0.0f;
            attn16[(size_t)i * 8 + h] = (u16)f2bf(es);
            den += es;
        }
    }
    den += __shfl_xor(den, 8);
    den += __shfl_xor(den, 16);
    den += __shfl_xor(den, 32);
    if (lane < 8) inv[node * 8 + lane] = (den > 0.0f) ? 1.0f / den : 0.0f;
}

// ---------------- diffuse: one wave/node, 4 ch/thread, unguarded 8-edge main loop ----
__global__ __launch_bounds__(256) void diffuse_kernel(
        const int* __restrict__ offs, const int* __restrict__ srcs,
        const u16* __restrict__ attn16, const float* __restrict__ inv,
        const unsigned* __restrict__ hcur, unsigned* __restrict__ hnext,
        uint2* __restrict__ gb, float fact) {
    int gid = blockIdx.x * 256 + threadIdx.x;
    int node = gid >> 6;
    int j2 = gid & 63;
    int h = j2 >> 3;
    int beg = offs[node], end = offs[node + 1];
    float a0 = 0.0f, a1 = 0.0f, a2 = 0.0f, a3 = 0.0f;
    int i = beg;
    // full batches of 8: unconditional loads -> compiler clusters into one clause
    for (; i + 8 <= end; i += 8) {
        int sarr[8]; float aarr[8]; unsigned hv[8];
        #pragma unroll
        for (int t = 0; t < 8; ++t) {
            sarr[t] = srcs[i + t];
            aarr[t] = bf16u(attn16[(size_t)(i + t) * 8 + h]);
        }
        #pragma unroll
        for (int t = 0; t < 8; ++t) hv[t] = hcur[(size_t)sarr[t] * 64 + j2];
        #pragma unroll
        for (int t = 0; t < 8; ++t) {
            float a = aarr[t];
            f32x2 lo = __builtin_amdgcn_cvt_pk_f32_fp8(hv[t], false);
            f32x2 hi = __builtin_amdgcn_cvt_pk_f32_fp8(hv[t], true);
            a0 += a * lo.x; a1 += a * lo.y;
            a2 += a * hi.x; a3 += a * hi.y;
        }
    }
    // remainder (guarded)
    if (i < end) {
        int cnt = end - i;
        int sarr[8]; float aarr[8]; unsigned hv[8];
        #pragma unroll
        for (int t = 0; t < 8; ++t) if (t < cnt) {
            sarr[t] = srcs[i + t];
            aarr[t] = bf16u(attn16[(size_t)(i + t) * 8 + h]);
        }
        #pragma unroll
        for (int t = 0; t < 8; ++t) if (t < cnt) hv[t] = hcur[(size_t)sarr[t] * 64 + j2];
        #pragma unroll
        for (int t = 0; t < 8; ++t) if (t < cnt) {
            float a = aarr[t];
            f32x2 lo = __builtin_amdgcn_cvt_pk_f32_fp8(hv[t], false);
            f32x2 hi = __builtin_amdgcn_cvt_pk_f32_fp8(hv[t], true);
            a0 += a * lo.x; a1 += a * lo.y;
            a2 += a * hi.x; a3 += a * hi.y;
        }
    }
    float iv = inv[node * 8 + h];
    a0 *= iv; a1 *= iv; a2 *= iv; a3 *= iv;    // normalized contribution
    if (hnext) {
        int pk = __builtin_amdgcn_cvt_pk_fp8_f32(a0, a1, 0, false);
        pk = __builtin_amdgcn_cvt_pk_fp8_f32(a2, a3, pk, true);
        hnext[(size_t)node * 64 + j2] = (unsigned)pk;
    }
    uint2* gp = gb + (size_t)node * 64 + j2;
    uint2 g = *gp;
    *gp = make_uint2(pack2bf(bf_lo(g.x) + fact * a0, bf_hi(g.x) + fact * a1),
                     pack2bf(bf_lo(g.y) + fact * a2, bf_hi(g.y) + fact * a3));
}

// ---------------- GEMM2 (64x256 tile) + residual + fused LayerNorm ----------------
__global__ __launch_bounds__(256) void gemm2_ln_kernel(
        const u16* __restrict__ Ab, const u16* __restrict__ Bt,
        const float* __restrict__ bias, const float* __restrict__ resid,
        const float* __restrict__ gamma, const float* __restrict__ beta,
        float* __restrict__ out) {
    __shared__ u16 As[64 * 40];
    __shared__ u16 Bs[256 * 40];
    const int tid = threadIdx.x;
    const int m0 = blockIdx.x * 64;
    const int wave = tid >> 6, lane = tid & 63;
    const int lm = lane & 15, quad = lane >> 4;

    f32x4 acc[16] = {};
    for (int k0 = 0; k0 < 256; k0 += 32) {
        *(uint4*)&As[(tid >> 2) * 40 + (tid & 3) * 8] =
            *(const uint4*)(Ab + (size_t)(m0 + (tid >> 2)) * 256 + k0 + (tid & 3) * 8);
        {
            const uint4* srcp = (const uint4*)(Bt + (size_t)tid * 256 + k0);
            uint4* dstp = (uint4*)&Bs[tid * 40];
            dstp[0] = srcp[0]; dstp[1] = srcp[1]; dstp[2] = srcp[2]; dstp[3] = srcp[3];
        }
        __syncthreads();
        bf16x8 af = *(const bf16x8*)&As[(wave * 16 + lm) * 40 + quad * 8];
        #pragma unroll
        for (int ni = 0; ni < 16; ++ni) {
            bf16x8 bfv = *(const bf16x8*)&Bs[(ni * 16 + lm) * 40 + quad * 8];
            acc[ni] = __builtin_amdgcn_mfma_f32_16x16x32_bf16(af, bfv, acc[ni], 0, 0, 0);
        }
        __syncthreads();
    }

    const int mrow = m0 + wave * 16 + quad * 4;
    float ga[16], be[16];
    float rowsum[4] = {}, rowsq[4] = {};
    #pragma unroll
    for (int ni = 0; ni < 16; ++ni) {
        int col = ni * 16 + lm;
        float bia = bias[col];
        ga[ni] = gamma[col]; be[ni] = beta[col];
        #pragma unroll
        for (int j = 0; j < 4; ++j) {
            float val = acc[ni][j] + bia + resid[(size_t)(mrow + j) * 256 + col];
            acc[ni][j] = val;
            rowsum[j] += val;
            rowsq[j] += val * val;
        }
    }
    #pragma unroll
    for (int j = 0; j < 4; ++j) {
        #pragma unroll
        for (int msk = 1; msk <= 8; msk <<= 1) {
            rowsum[j] += __shfl_xor(rowsum[j], msk);
            rowsq[j] += __shfl_xor(rowsq[j], msk);
        }
    }
    float mu[4], rstd[4];
    #pragma unroll
    for (int j = 0; j < 4; ++j) {
        mu[j] = rowsum[j] * (1.0f / 256.0f);
        float var = rowsq[j] * (1.0f / 256.0f) - mu[j] * mu[j];
        rstd[j] = 1.0f / sqrtf(var + LN_EPS);
    }
    #pragma unroll
    for (int ni = 0; ni < 16; ++ni) {
        int col = ni * 16 + lm;
        #pragma unroll
        for (int j = 0; j < 4; ++j)
            out[(size_t)(mrow + j) * 256 + col] = (acc[ni][j] - mu[j]) * rstd[j] * ga[ni] + be[ni];
    }
}

extern "C" void kernel_launch(void* const* d_in, const int* in_sizes, int n_in,
                              void* d_out, int out_size, void* d_ws, size_t ws_size,
                              hipStream_t stream) {
    const float* hidden = (const float*)d_in[0];
    const float* amask  = (const float*)d_in[1];
    const int*   src    = (const int*)d_in[2];
    const int*   dst    = (const int*)d_in[3];
    const float* Wqkv   = (const float*)d_in[4];
    const float* bqkv   = (const float*)d_in[5];
    const float* Wo     = (const float*)d_in[6];
    const float* bo     = (const float*)d_in[7];
    const float* gamma  = (const float*)d_in[8];
    const float* beta   = (const float*)d_in[9];
    float* out = (float*)d_out;

    char* p = (char*)d_ws;
    u16*      hidb   = (u16*)p;      p += (size_t)NN * DD * 2;     // 8 MB
    u16*      WtQ    = (u16*)p;      p += (size_t)D3 * DD * 2;
    u16*      WtO    = (u16*)p;      p += (size_t)DD * DD * 2;
    float*    biasq  = (float*)p;    p += (size_t)D3 * 4;
    float*    biaso  = (float*)p;    p += (size_t)DD * 4;
    u16*      qb     = (u16*)p;      p += (size_t)NN * DD * 2;     // 8 MB bf16
    u8*       kb8    = (u8*)p;       p += (size_t)NN * DD;         // 4 MB fp8
    u8*       h8A    = (u8*)p;       p += (size_t)NN * DD;         // 4 MB fp8
    u8*       h8B    = (u8*)p;       p += (size_t)NN * DD;         // 4 MB fp8
    u16*      gb     = (u16*)p;      p += (size_t)NN * DD * 2;     // 8 MB bf16 gather acc
    u16*      attn16 = (u16*)p;      p += (size_t)EE * HH * 2;     // 4 MB bf16 unnorm exp
    float*    inv    = (float*)p;    p += (size_t)NN * HH * 4;     // 0.5 MB
    int*      deg    = (int*)p;      p += (size_t)NN * 4;
    int*      offs   = (int*)p;      p += (size_t)(NN + 1) * 4;
    int*      cursor = (int*)p;      p += (size_t)NN * 4;
    int*      srcs   = (int*)p;      p += (size_t)EE * 4;

    // 1. zero degree histogram, then fused prep (convs + hist)
    hipMemsetAsync(deg, 0, (size_t)NN * 4, stream);
    prep_kernel<<<6144, 256, 0, stream>>>(hidden, (unsigned*)hidb,
                                          Wqkv, bqkv, WtQ, biasq,
                                          Wo, bo, WtO, biaso, dst, deg);

    // 2. CSR scan
    scan_kernel<<<1, 1024, 0, stream>>>(deg, offs, cursor, NN);

    // 3. QKV projection (MFMA, blocks 0..767) || CSR scatter (blocks 768..1791)
    gemm1_scatter_kernel<<<1792, 256, 0, stream>>>(
        hidb, WtQ, biasq, qb, kb8, h8A, gb, src, dst, cursor, srcs);

    // 4. edge scores + softmax (single pass, bf16 unnorm exp + inv)
    edge_softmax_kernel<<<NN / 4, 256, 0, stream>>>(
        (const unsigned*)qb, kb8, offs, srcs, amask, attn16, inv);

    // 5. diffusion: gb = h0 + h1 + h2/2 + h3/6
    diffuse_kernel<<<(NN * 64) / 256, 256, 0, stream>>>(
        offs, srcs, attn16, inv, (const unsigned*)h8A, (unsigned*)h8B, (uint2*)gb, 1.0f);
    diffuse_kernel<<<(NN * 64) / 256, 256, 0, stream>>>(
        offs, srcs, attn16, inv, (const unsigned*)h8B, (unsigned*)h8A, (uint2*)gb, 0.5f);
    diffuse_kernel<<<(NN * 64) / 256, 256, 0, stream>>>(
        offs, srcs, attn16, inv, (const unsigned*)h8A, nullptr, (uint2*)gb, 1.0f / 6.0f);

    // 6. output projection + residual + fused LayerNorm -> out
    gemm2_ln_kernel<<<NN / 64, 256, 0, stream>>>(
        gb, WtO, biaso, hidden, gamma, beta, out);
}